// Round 18
// baseline (148.249 us; speedup 1.0000x reference)
//
#include <hip/hip_runtime.h>
#include <math.h>

#define N 8192
#define WSP (80*N)          // per-attend workspace floats
#define OFF_G (8*N)         // G bf16 hi/lo [N][16] ushort
#define OFF_T (16*N)        // vb fp32 (prep) -> per-chunk bf16 tiles (rownorm)
// F at base: [N][16] ushort = row n: fh[0..7], fl[0..7]  (f pre-scaled by log2e)
// G at OFF_G: same layout for g.
// vb at OFF_T (prep->rownorm): CHANNEL-MAJOR [64][N] fp32 (coalesced both ways).
// tiles after rownorm (in place over vb): per 32-row chunk b (4096 ushorts):
//   ushort tileH[64][32]; row c, position q holds vt[n0+sigma(q)][c],
//   sigma(q) = 32x32 MFMA C/D row perm -> exp2(S) packs DIRECTLY into PV B-frags.
// CONSISTENT TRUNCATION: attn uses p~ = bf16trunc(exp2(S)) as PV weights;
// rownorm sums the SAME truncated values into l -> truncation bias divides out.
// S computed by IDENTICAL 3-term MFMA sequence in both kernels.

typedef __attribute__((ext_vector_type(8)))  short bf16x8;
typedef __attribute__((ext_vector_type(4)))  float f32x4;
typedef __attribute__((ext_vector_type(16))) float f32x16;

#define ZERO16 ((f32x16){0.f,0.f,0.f,0.f,0.f,0.f,0.f,0.f,0.f,0.f,0.f,0.f,0.f,0.f,0.f,0.f})

#if defined(__has_builtin)
#  if __has_builtin(__builtin_amdgcn_exp2f)
#    define EXP2(x) __builtin_amdgcn_exp2f(x)
#  endif
#endif
#ifndef EXP2
#  define EXP2(x) exp2f(x)
#endif

__device__ __forceinline__ unsigned short bf_hi(float x) {
    union { float f; unsigned u; } v; v.f = x;
    unsigned r = v.u + 0x7fffu + ((v.u >> 16) & 1u);   // round-to-nearest-even
    return (unsigned short)(r >> 16);
}
__device__ __forceinline__ float bf_f(unsigned short h) {
    union { float f; unsigned u; } v; v.u = ((unsigned)h) << 16;
    return v.f;
}
// pack hi16 of two fp32 bit-patterns: (i1 & 0xffff0000) | (i0 >> 16)
__device__ __forceinline__ unsigned pack_hi16(unsigned i1, unsigned i0) {
#if defined(__has_builtin) && __has_builtin(__builtin_amdgcn_perm)
    return __builtin_amdgcn_perm(i1, i0, 0x07060302u);   // v_perm_b32
#else
    return (i1 & 0xffff0000u) | (i0 >> 16);
#endif
}

// XCD-segregation: attend 0 on XCDs 0-3, attend 1 on XCDs 4-7.
__device__ __forceinline__ void xcd_map(int lin, int& a, int& idx) {
    int xcd = lin & 7;
    a   = xcd >> 2;
    idx = (xcd & 3) | ((lin >> 3) << 2);
}

// ---------------------------------------------------------------------------
// Kernel 0: projections (W staged in LDS, float4 LDS reads, coalesced vb).
// Unchanged.
// ---------------------------------------------------------------------------
__global__ __launch_bounds__(512) void prep_kernel(
    const float* __restrict__ x1, const float* __restrict__ x2,
    const float* __restrict__ Wf, const float* __restrict__ bf,
    const float* __restrict__ Wg, const float* __restrict__ bg,
    const float* __restrict__ Wh1, const float* __restrict__ bh1,
    const float* __restrict__ Wh2, const float* __restrict__ bh2,
    float* __restrict__ ws)
{
    int a, bidx;
    xcd_map(blockIdx.x + (int)gridDim.x * blockIdx.y, a, bidx);   // lin 0..511
    const float* x  = a ? x2  : x1;
    const float* Wh = a ? Wh2 : Wh1;
    const float* bh = a ? bh2 : bh1;
    float* base = ws + (size_t)a * WSP;
    unsigned short* F16 = (unsigned short*)base;           // [N][16]
    unsigned short* G16 = (unsigned short*)(base + OFF_G); // [N][16]
    float* vb = base + OFF_T;                              // [64][N] fp32

    __shared__ __align__(16) float xs[32][68];    // x transposed: xs[j][c]
    __shared__ __align__(16) float Wlds[80][64];  // rows: Wf 0-7, Wg 8-15, Wh 16-79
    __shared__ float blds[80];

    const int n0 = bidx * 32;
    const int t  = threadIdx.x;
    for (int i = t; i < 64*32; i += 512) {
        int c = i >> 5, j = i & 31;
        xs[j][c] = x[(size_t)c*N + n0 + j];
    }
    // W staged as float4 (rows are 256B-aligned in source)
    for (int i4 = t; i4 < 80*16; i4 += 512) {
        int o = i4 >> 4, c4 = i4 & 15;
        const float* src = (o < 8) ? (Wf + o*64) : (o < 16) ? (Wg + (o-8)*64) : (Wh + (o-16)*64);
        *(f32x4*)&Wlds[o][c4*4] = *(const f32x4*)(src + c4*4);
    }
    if (t < 80) blds[t] = (t < 8) ? bf[t] : (t < 16) ? bg[t-8] : bh[t-16];
    __syncthreads();

    const int j  = t & 31;
    const int og = t >> 5;            // 0..15; outputs o = og + 16k, k=0..4
    float s[5];
    #pragma unroll
    for (int k = 0; k < 5; ++k) s[k] = blds[og + 16*k];
    const f32x4* xrow = (const f32x4*)&xs[j][0];
    #pragma unroll 4
    for (int c4 = 0; c4 < 16; ++c4) {
        const f32x4 xv = xrow[c4];
        #pragma unroll
        for (int k = 0; k < 5; ++k) {
            const f32x4 wv = *(const f32x4*)&Wlds[og + 16*k][c4*4];
            s[k] += wv.x * xv.x;
            s[k] += wv.y * xv.y;
            s[k] += wv.z * xv.z;
            s[k] += wv.w * xv.w;
        }
    }
    const float LOG2E = 1.44269504088896340736f;
    #pragma unroll
    for (int k = 0; k < 5; ++k) {
        int o = og + 16*k;
        if (o < 8) {
            float v = s[k] * LOG2E;
            unsigned short h = bf_hi(v);
            F16[(size_t)(n0+j)*16 + o]     = h;
            F16[(size_t)(n0+j)*16 + 8 + o] = bf_hi(v - bf_f(h));
        } else if (o < 16) {
            float v = s[k];
            unsigned short h = bf_hi(v);
            G16[(size_t)(n0+j)*16 + (o-8)]     = h;
            G16[(size_t)(n0+j)*16 + 8 + (o-8)] = bf_hi(v - bf_f(h));
        } else {
            vb[(size_t)(o-16)*N + n0 + j] = s[k];   // channel-major: coalesced
        }
    }
}

// ---------------------------------------------------------------------------
// Kernel 1: l[n] = sum_m bf16trunc(exp2(S)) via MFMA logits, S-pipelined.
// Unchanged.
// ---------------------------------------------------------------------------
__global__ __launch_bounds__(512, 4) void rownorm_kernel(float* __restrict__ ws)
{
    int a, bidx;
    xcd_map(blockIdx.x + (int)gridDim.x * blockIdx.y, a, bidx);   // lin 0..511
    float* base = ws + (size_t)a * WSP;
    const unsigned short* F16 = (const unsigned short*)base;
    const unsigned short* G16 = (const unsigned short*)(base + OFF_G);
    float* vb = base + OFF_T;                              // [64][N]
    const int n0 = bidx * 32;
    const int t  = threadIdx.x;
    const int w = t >> 6, lane = t & 63, l31 = lane & 31, hi = lane >> 5;

    __shared__ float vbs[32][65];   // staged v rows (in-place overwrite safety); +1 pad
    __shared__ float lsum[8][32];
    __shared__ float linv[32];

    {   // vb read exactly once -> non-temporal; [64][N]: 8 lanes cover one 128B c-run
        const int c = t >> 3, g = t & 7;
        const f32x4 v = __builtin_nontemporal_load(
            (const f32x4*)(vb + (size_t)c*N + n0 + g*4));
        vbs[g*4+0][c] = v.x;
        vbs[g*4+1][c] = v.y;
        vbs[g*4+2][c] = v.z;
        vbs[g*4+3][c] = v.w;
    }

    // A fragment: rows n0..n0+31, hi half = fl octet (3-term hi/lo packing)
    const bf16x8 A1 = *(const bf16x8*)(F16 + (size_t)(n0 + l31)*16 + hi*8);
    const bf16x8 z8 = {0,0,0,0,0,0,0,0};
    const bf16x8 A2 = hi ? z8 : A1;      // [fh ; 0]

    const int mb = w * (N/8);
    const int MM = (N/8) - 1;
    bf16x8 B1, B2;
    f32x16 S, sum = ZERO16;

    // prologue: S(0); B(1) in flight
    B1 = *(const bf16x8*)(G16 + (size_t)(mb + l31)*16);
    B2 = *(const bf16x8*)(G16 + (size_t)(mb + l31)*16 + 8);
    S = __builtin_amdgcn_mfma_f32_32x32x16_bf16(A1, B1, ZERO16, 0, 0, 0);
    S = __builtin_amdgcn_mfma_f32_32x32x16_bf16(A2, B2, S, 0, 0, 0);
    B1 = *(const bf16x8*)(G16 + (size_t)(mb + 32 + l31)*16);
    B2 = *(const bf16x8*)(G16 + (size_t)(mb + 32 + l31)*16 + 8);

    for (int it = 0; it < 32; ++it) {
        // S(it+1) on the MFMA pipe (independent of exp2 below)
        f32x16 Sn = __builtin_amdgcn_mfma_f32_32x32x16_bf16(A1, B1, ZERO16, 0, 0, 0);
        Sn = __builtin_amdgcn_mfma_f32_32x32x16_bf16(A2, B2, Sn, 0, 0, 0);
        // B(it+2), wrapped
        {
            const size_t mrow = mb + (((it+2)*32) & MM) + l31;
            B1 = *(const bf16x8*)(G16 + mrow*16);
            B2 = *(const bf16x8*)(G16 + mrow*16 + 8);
        }
        // consume S(it) on the VALU: accumulate TRUNCATED p (matches attn PV)
        #pragma unroll
        for (int r = 0; r < 16; ++r)
            sum[r] += __uint_as_float(__float_as_uint(EXP2(S[r])) & 0xffff0000u);
        S = Sn;
    }
    #pragma unroll
    for (int r = 0; r < 16; ++r) {
        float v = sum[r];
        v += __shfl_xor(v, 1, 64);
        v += __shfl_xor(v, 2, 64);
        v += __shfl_xor(v, 4, 64);
        v += __shfl_xor(v, 8, 64);
        v += __shfl_xor(v, 16, 64);
        sum[r] = v;
    }
    if (l31 == 0) {
        #pragma unroll
        for (int r = 0; r < 16; ++r) {
            int n = (r & 3) + 8*(r >> 2) + 4*hi;
            lsum[w][n] = sum[r];
        }
    }
    __syncthreads();
    if (t < 32) {
        float v = 0.f;
        #pragma unroll
        for (int ww = 0; ww < 8; ++ww) v += lsum[ww][t];
        linv[t] = 1.0f / v;
    }
    __syncthreads();

    // emit tiles (H only): position kk holds vt[n0 + sigma(kk)][c]
    if (t < 256) {
        const int c = t >> 2, kkg = t & 3;
        bf16x8 H;
        #pragma unroll
        for (int jj = 0; jj < 8; ++jj) {
            int n_rd = (kkg >> 1)*16 + 4*(kkg & 1) + (jj & 3) + 8*((jj >> 2) & 1);
            H[jj] = (short)bf_hi(vbs[n_rd][c] * linv[n_rd]);
        }
        unsigned short* tile = (unsigned short*)(base + OFF_T) + (size_t)(n0 >> 5) * 4096;
        *(bf16x8*)(tile + c*32 + kkg*8) = H;
    }
}

// ---------------------------------------------------------------------------
// Kernel 2: sa[c][m] = sum_n bf16(vt[n][c]) * p~[n][m], p~ = bf16trunc(exp2(S)).
// TWO K-CHUNKS PER ITERATION (16 iters): two independent S-sets + two tile
// buffers -> 10 loads in flight per iter (2x MLP) and ~full-iteration
// refill->use distance for each buffer. Register demand (~204 unified) forces
// the buffers live at (512,2)'s 256-reg cap. Chunk order & MFMA sequence are
// bitwise-identical to the sequential version.
// ---------------------------------------------------------------------------
#define MFMA_(A_, B_, C_) __builtin_amdgcn_mfma_f32_32x32x16_bf16(A_, B_, C_, 0, 0, 0)

#define PACK_QUAD(P0_, P1_, S0_, S1_, O_)                                      \
    _Pragma("unroll")                                                          \
    for (int d = 0; d < 4; ++d) {                                              \
        float q0 = EXP2(S0_[(O_) + 2*d]), q1 = EXP2(S0_[(O_) + 2*d + 1]);      \
        P0_.u[d] = pack_hi16(__float_as_uint(q1), __float_as_uint(q0));        \
        float q2 = EXP2(S1_[(O_) + 2*d]), q3 = EXP2(S1_[(O_) + 2*d + 1]);      \
        P1_.u[d] = pack_hi16(__float_as_uint(q3), __float_as_uint(q2));        \
    }

#define CHUNK_PV(S0_, S1_, T0_, T1_, T2_, T3_)                                 \
    {                                                                          \
        BU u0_, u1_;                                                           \
        PACK_QUAD(u0_, u1_, S0_, S1_, 0)                                       \
        accA = MFMA_(T0_, u0_.v, accA);                                        \
        accC = MFMA_(T0_, u1_.v, accC);                                        \
        accB = MFMA_(T1_, u0_.v, accB);                                        \
        accD = MFMA_(T1_, u1_.v, accD);                                        \
        BU v0_, v1_;                                                           \
        PACK_QUAD(v0_, v1_, S0_, S1_, 8)                                       \
        accA = MFMA_(T2_, v0_.v, accA);                                        \
        accC = MFMA_(T2_, v1_.v, accC);                                        \
        accB = MFMA_(T3_, v0_.v, accB);                                        \
        accD = MFMA_(T3_, v1_.v, accD);                                        \
    }

#define LOAD_TILES(T0_, T1_, T2_, T3_, REL_)                                   \
    {                                                                          \
        const unsigned short* tb_ = tiles + (size_t)(cb + ((REL_) & 31)) * 4096; \
        T0_ = *(const bf16x8*)(tb_ + (0*32 + l31)*32 + 0*16 + hi*8);           \
        T1_ = *(const bf16x8*)(tb_ + (1*32 + l31)*32 + 0*16 + hi*8);           \
        T2_ = *(const bf16x8*)(tb_ + (0*32 + l31)*32 + 1*16 + hi*8);           \
        T3_ = *(const bf16x8*)(tb_ + (1*32 + l31)*32 + 1*16 + hi*8);           \
    }

#define LOAD_A(DST_, REL_)                                                     \
    DST_ = *(const bf16x8*)(F16 + (size_t)((cb + ((REL_) & 31))*32 + l31)*16 + hi*8);

#define LOGITS(S0_, S1_, A_)                                                   \
    S0_ = MFMA_(A_, Bh0, ZERO16); S1_ = MFMA_(A_, Bh1, ZERO16);                \
    S0_ = MFMA_(A_, Bl0, S0_);    S1_ = MFMA_(A_, Bl1, S1_);

__global__ __launch_bounds__(512, 2) void attn_kernel(
    const float* __restrict__ x1, const float* __restrict__ x2,
    const float* __restrict__ ga1, const float* __restrict__ ga2,
    const float* __restrict__ ws, float* __restrict__ out_)
{
    int a, bidx;
    xcd_map(blockIdx.x + (int)gridDim.x * blockIdx.y, a, bidx);   // lin 0..255
    const float* x = a ? x2 : x1;
    const float gamma = a ? ga2[0] : ga1[0];
    const float* base = ws + (size_t)a * WSP;
    const unsigned short* F16 = (const unsigned short*)base;
    const unsigned short* G16 = (const unsigned short*)(base + OFF_G);
    const unsigned short* tiles = (const unsigned short*)(base + OFF_T);
    float* out = out_ + (size_t)a * ((size_t)64 * N);

    const int m0 = bidx * 64;
    const int t = threadIdx.x;
    const int w = t >> 6, lane = t & 63, l31 = lane & 31, hi = lane >> 5;

    // g fragments for the wave's TWO 32-col m-groups (resident all kernel)
    const bf16x8 z8 = {0,0,0,0,0,0,0,0};
    bf16x8 Bh0, Bl0, Bh1, Bl1;
    {
        const unsigned short* gp0 = G16 + (size_t)(m0 + l31)*16;
        const unsigned short* gp1 = G16 + (size_t)(m0 + 32 + l31)*16;
        Bh0 = *(const bf16x8*)gp0;
        Bl0 = hi ? z8 : *(const bf16x8*)(gp0 + 8);
        Bh1 = *(const bf16x8*)gp1;
        Bl1 = hi ? z8 : *(const bf16x8*)(gp1 + 8);
    }

    f32x16 accA = ZERO16, accB = ZERO16;   // mg0: ct=0, ct=1
    f32x16 accC = ZERO16, accD = ZERO16;   // mg1: ct=0, ct=1

    const int cb = w * 32;                 // chunk base: 32 chunks of 32 rows/wave

    union BU { bf16x8 v; unsigned u[4]; };

    bf16x8 Aa, Ab;                         // A-frags for NEXT logits (chunks 2it+2/3)
    bf16x8 AHa0, AHa1, AHa2, AHa3;         // tiles, chunk 2it
    bf16x8 AHb0, AHb1, AHb2, AHb3;         // tiles, chunk 2it+1
    f32x16 Sa0, Sa1, Sb0, Sb1;             // logits, chunks 2it / 2it+1

    // prologue: S for chunks 0,1; tiles 0,1; A for chunks 2,3
    {
        bf16x8 A0; LOAD_A(A0, 0)
        LOGITS(Sa0, Sa1, A0)
        bf16x8 A1v; LOAD_A(A1v, 1)
        LOGITS(Sb0, Sb1, A1v)
    }
    LOAD_TILES(AHa0, AHa1, AHa2, AHa3, 0)
    LOAD_TILES(AHb0, AHb1, AHb2, AHb3, 1)
    LOAD_A(Aa, 2)
    LOAD_A(Ab, 3)

    for (int it = 0; it < 16; ++it) {
        CHUNK_PV(Sa0, Sa1, AHa0, AHa1, AHa2, AHa3)
        LOAD_TILES(AHa0, AHa1, AHa2, AHa3, 2*it + 2)
        CHUNK_PV(Sb0, Sb1, AHb0, AHb1, AHb2, AHb3)
        LOAD_TILES(AHb0, AHb1, AHb2, AHb3, 2*it + 3)
        LOGITS(Sa0, Sa1, Aa)
        LOGITS(Sb0, Sb1, Ab)
        LOAD_A(Aa, 2*it + 4)
        LOAD_A(Ab, 2*it + 5)
    }

    // cross-wave (K-split) reduction over 8 waves; 64c x 64m block tile
    __shared__ float red[64][65];
    for (int ww = 0; ww < 8; ++ww) {
        if (w == ww) {
            #pragma unroll
            for (int mg = 0; mg < 2; ++mg)
                #pragma unroll
                for (int ct = 0; ct < 2; ++ct) {
                    const f32x16& Ac = mg ? (ct ? accD : accC) : (ct ? accB : accA);
                    #pragma unroll
                    for (int r = 0; r < 16; ++r) {
                        int c = ct*32 + (r & 3) + 8*(r >> 2) + 4*hi;   // C/D row map
                        int m = mg*32 + l31;
                        if (ww == 0) red[c][m]  = Ac[r];
                        else         red[c][m] += Ac[r];
                    }
                }
        }
        __syncthreads();
    }
    #pragma unroll
    for (int i = 0; i < 8; ++i) {
        int e = t + 512*i;
        int c = e >> 6, m = e & 63;
        size_t gi = (size_t)c*N + m0 + m;
        float xv = __builtin_nontemporal_load(x + gi);
        __builtin_nontemporal_store(gamma * red[c][m] + xv, out + gi);
    }
}

// ---------------------------------------------------------------------------
extern "C" void kernel_launch(void* const* d_in, const int* in_sizes, int n_in,
                              void* d_out, int out_size, void* d_ws, size_t ws_size,
                              hipStream_t stream)
{
    (void)in_sizes; (void)n_in; (void)out_size; (void)ws_size;
    const float* x1  = (const float*)d_in[0];
    const float* x2  = (const float*)d_in[1];
    const float* Wf  = (const float*)d_in[2];
    const float* bf  = (const float*)d_in[3];
    const float* Wg  = (const float*)d_in[4];
    const float* bg  = (const float*)d_in[5];
    const float* Wh1 = (const float*)d_in[6];
    const float* bh1 = (const float*)d_in[7];
    const float* Wh2 = (const float*)d_in[8];
    const float* bh2 = (const float*)d_in[9];
    const float* g1  = (const float*)d_in[10];
    const float* g2  = (const float*)d_in[11];
    float* out = (float*)d_out;
    float* ws  = (float*)d_ws;

    prep_kernel   <<<dim3(N/32, 2), dim3(512), 0, stream>>>(x1,x2,Wf,bf,Wg,bg,Wh1,bh1,Wh2,bh2,ws);
    rownorm_kernel<<<dim3(N/32, 2), dim3(512), 0, stream>>>(ws);
    attn_kernel   <<<dim3(N/64, 2), dim3(512), 0, stream>>>(x1,x2,g1,g2,ws,out);
}

// Round 19
// 137.248 us; speedup vs baseline: 1.0802x; 1.0802x over previous
//
#include <hip/hip_runtime.h>
#include <math.h>

#define N 8192
#define WSP (80*N)          // per-attend workspace floats
#define OFF_G (8*N)         // G bf16 hi/lo [N][16] ushort
#define OFF_T (16*N)        // vb fp32 (prep) -> per-chunk bf16 tiles (rownorm)
// F at base: [N][16] ushort = row n: fh[0..7], fl[0..7]  (f pre-scaled by log2e)
// G at OFF_G: same layout for g.
// vb at OFF_T (prep->rownorm): CHANNEL-MAJOR [64][N] fp32 (coalesced both ways).
// tiles after rownorm (in place over vb): per 32-row chunk b (4096 ushorts):
//   ushort tileH[64][32]; row c, position q holds vt[n0+sigma(q)][c],
//   sigma(q) = 32x32 MFMA C/D row perm -> exp2(S) packs DIRECTLY into PV B-frags.
// CONSISTENT TRUNCATION: attn uses p~ = bf16trunc(exp2(S)) as PV weights;
// rownorm sums the SAME truncated values into l -> truncation bias divides out.
// S computed by IDENTICAL 3-term MFMA sequence in both kernels.

typedef __attribute__((ext_vector_type(8)))  short bf16x8;
typedef __attribute__((ext_vector_type(4)))  float f32x4;
typedef __attribute__((ext_vector_type(16))) float f32x16;

#define ZERO16 ((f32x16){0.f,0.f,0.f,0.f,0.f,0.f,0.f,0.f,0.f,0.f,0.f,0.f,0.f,0.f,0.f,0.f})

#if defined(__has_builtin)
#  if __has_builtin(__builtin_amdgcn_exp2f)
#    define EXP2(x) __builtin_amdgcn_exp2f(x)
#  endif
#endif
#ifndef EXP2
#  define EXP2(x) exp2f(x)
#endif

__device__ __forceinline__ unsigned short bf_hi(float x) {
    union { float f; unsigned u; } v; v.f = x;
    unsigned r = v.u + 0x7fffu + ((v.u >> 16) & 1u);   // round-to-nearest-even
    return (unsigned short)(r >> 16);
}
__device__ __forceinline__ float bf_f(unsigned short h) {
    union { float f; unsigned u; } v; v.u = ((unsigned)h) << 16;
    return v.f;
}
// pack hi16 of two fp32 bit-patterns: (i1 & 0xffff0000) | (i0 >> 16)
__device__ __forceinline__ unsigned pack_hi16(unsigned i1, unsigned i0) {
#if defined(__has_builtin) && __has_builtin(__builtin_amdgcn_perm)
    return __builtin_amdgcn_perm(i1, i0, 0x07060302u);   // v_perm_b32
#else
    return (i1 & 0xffff0000u) | (i0 >> 16);
#endif
}

// XCD-segregation: attend 0 on XCDs 0-3, attend 1 on XCDs 4-7.
__device__ __forceinline__ void xcd_map(int lin, int& a, int& idx) {
    int xcd = lin & 7;
    a   = xcd >> 2;
    idx = (xcd & 3) | ((lin >> 3) << 2);
}

// ---------------------------------------------------------------------------
// Kernel 0: projections (W staged in LDS, float4 LDS reads, coalesced vb).
// ---------------------------------------------------------------------------
__global__ __launch_bounds__(512) void prep_kernel(
    const float* __restrict__ x1, const float* __restrict__ x2,
    const float* __restrict__ Wf, const float* __restrict__ bf,
    const float* __restrict__ Wg, const float* __restrict__ bg,
    const float* __restrict__ Wh1, const float* __restrict__ bh1,
    const float* __restrict__ Wh2, const float* __restrict__ bh2,
    float* __restrict__ ws)
{
    int a, bidx;
    xcd_map(blockIdx.x + (int)gridDim.x * blockIdx.y, a, bidx);   // lin 0..511
    const float* x  = a ? x2  : x1;
    const float* Wh = a ? Wh2 : Wh1;
    const float* bh = a ? bh2 : bh1;
    float* base = ws + (size_t)a * WSP;
    unsigned short* F16 = (unsigned short*)base;           // [N][16]
    unsigned short* G16 = (unsigned short*)(base + OFF_G); // [N][16]
    float* vb = base + OFF_T;                              // [64][N] fp32

    __shared__ __align__(16) float xs[32][68];    // x transposed: xs[j][c]
    __shared__ __align__(16) float Wlds[80][64];  // rows: Wf 0-7, Wg 8-15, Wh 16-79
    __shared__ float blds[80];

    const int n0 = bidx * 32;
    const int t  = threadIdx.x;
    for (int i = t; i < 64*32; i += 512) {
        int c = i >> 5, j = i & 31;
        xs[j][c] = x[(size_t)c*N + n0 + j];
    }
    // W staged as float4 (rows are 256B-aligned in source)
    for (int i4 = t; i4 < 80*16; i4 += 512) {
        int o = i4 >> 4, c4 = i4 & 15;
        const float* src = (o < 8) ? (Wf + o*64) : (o < 16) ? (Wg + (o-8)*64) : (Wh + (o-16)*64);
        *(f32x4*)&Wlds[o][c4*4] = *(const f32x4*)(src + c4*4);
    }
    if (t < 80) blds[t] = (t < 8) ? bf[t] : (t < 16) ? bg[t-8] : bh[t-16];
    __syncthreads();

    const int j  = t & 31;
    const int og = t >> 5;            // 0..15; outputs o = og + 16k, k=0..4
    float s[5];
    #pragma unroll
    for (int k = 0; k < 5; ++k) s[k] = blds[og + 16*k];
    const f32x4* xrow = (const f32x4*)&xs[j][0];
    #pragma unroll 4
    for (int c4 = 0; c4 < 16; ++c4) {
        const f32x4 xv = xrow[c4];
        #pragma unroll
        for (int k = 0; k < 5; ++k) {
            const f32x4 wv = *(const f32x4*)&Wlds[og + 16*k][c4*4];
            s[k] += wv.x * xv.x;
            s[k] += wv.y * xv.y;
            s[k] += wv.z * xv.z;
            s[k] += wv.w * xv.w;
        }
    }
    const float LOG2E = 1.44269504088896340736f;
    #pragma unroll
    for (int k = 0; k < 5; ++k) {
        int o = og + 16*k;
        if (o < 8) {
            float v = s[k] * LOG2E;
            unsigned short h = bf_hi(v);
            F16[(size_t)(n0+j)*16 + o]     = h;
            F16[(size_t)(n0+j)*16 + 8 + o] = bf_hi(v - bf_f(h));
        } else if (o < 16) {
            float v = s[k];
            unsigned short h = bf_hi(v);
            G16[(size_t)(n0+j)*16 + (o-8)]     = h;
            G16[(size_t)(n0+j)*16 + 8 + (o-8)] = bf_hi(v - bf_f(h));
        } else {
            vb[(size_t)(o-16)*N + n0 + j] = s[k];   // channel-major: coalesced
        }
    }
}

// ---------------------------------------------------------------------------
// Kernel 1: l[n] = sum_m bf16trunc(exp2(S)) via MFMA logits, S-pipelined.
// ---------------------------------------------------------------------------
__global__ __launch_bounds__(512, 4) void rownorm_kernel(float* __restrict__ ws)
{
    int a, bidx;
    xcd_map(blockIdx.x + (int)gridDim.x * blockIdx.y, a, bidx);   // lin 0..511
    float* base = ws + (size_t)a * WSP;
    const unsigned short* F16 = (const unsigned short*)base;
    const unsigned short* G16 = (const unsigned short*)(base + OFF_G);
    float* vb = base + OFF_T;                              // [64][N]
    const int n0 = bidx * 32;
    const int t  = threadIdx.x;
    const int w = t >> 6, lane = t & 63, l31 = lane & 31, hi = lane >> 5;

    __shared__ float vbs[32][65];   // staged v rows (in-place overwrite safety); +1 pad
    __shared__ float lsum[8][32];
    __shared__ float linv[32];

    {   // vb read exactly once -> non-temporal; [64][N]: 8 lanes cover one 128B c-run
        const int c = t >> 3, g = t & 7;
        const f32x4 v = __builtin_nontemporal_load(
            (const f32x4*)(vb + (size_t)c*N + n0 + g*4));
        vbs[g*4+0][c] = v.x;
        vbs[g*4+1][c] = v.y;
        vbs[g*4+2][c] = v.z;
        vbs[g*4+3][c] = v.w;
    }

    // A fragment: rows n0..n0+31, hi half = fl octet (3-term hi/lo packing)
    const bf16x8 A1 = *(const bf16x8*)(F16 + (size_t)(n0 + l31)*16 + hi*8);
    const bf16x8 z8 = {0,0,0,0,0,0,0,0};
    const bf16x8 A2 = hi ? z8 : A1;      // [fh ; 0]

    const int mb = w * (N/8);
    const int MM = (N/8) - 1;
    bf16x8 B1, B2;
    f32x16 S, sum = ZERO16;

    // prologue: S(0); B(1) in flight
    B1 = *(const bf16x8*)(G16 + (size_t)(mb + l31)*16);
    B2 = *(const bf16x8*)(G16 + (size_t)(mb + l31)*16 + 8);
    S = __builtin_amdgcn_mfma_f32_32x32x16_bf16(A1, B1, ZERO16, 0, 0, 0);
    S = __builtin_amdgcn_mfma_f32_32x32x16_bf16(A2, B2, S, 0, 0, 0);
    B1 = *(const bf16x8*)(G16 + (size_t)(mb + 32 + l31)*16);
    B2 = *(const bf16x8*)(G16 + (size_t)(mb + 32 + l31)*16 + 8);

    for (int it = 0; it < 32; ++it) {
        // S(it+1) on the MFMA pipe (independent of exp2 below)
        f32x16 Sn = __builtin_amdgcn_mfma_f32_32x32x16_bf16(A1, B1, ZERO16, 0, 0, 0);
        Sn = __builtin_amdgcn_mfma_f32_32x32x16_bf16(A2, B2, Sn, 0, 0, 0);
        // B(it+2), wrapped
        {
            const size_t mrow = mb + (((it+2)*32) & MM) + l31;
            B1 = *(const bf16x8*)(G16 + mrow*16);
            B2 = *(const bf16x8*)(G16 + mrow*16 + 8);
        }
        // consume S(it) on the VALU: accumulate TRUNCATED p (matches attn PV)
        #pragma unroll
        for (int r = 0; r < 16; ++r)
            sum[r] += __uint_as_float(__float_as_uint(EXP2(S[r])) & 0xffff0000u);
        S = Sn;
    }
    #pragma unroll
    for (int r = 0; r < 16; ++r) {
        float v = sum[r];
        v += __shfl_xor(v, 1, 64);
        v += __shfl_xor(v, 2, 64);
        v += __shfl_xor(v, 4, 64);
        v += __shfl_xor(v, 8, 64);
        v += __shfl_xor(v, 16, 64);
        sum[r] = v;
    }
    if (l31 == 0) {
        #pragma unroll
        for (int r = 0; r < 16; ++r) {
            int n = (r & 3) + 8*(r >> 2) + 4*hi;
            lsum[w][n] = sum[r];
        }
    }
    __syncthreads();
    if (t < 32) {
        float v = 0.f;
        #pragma unroll
        for (int ww = 0; ww < 8; ++ww) v += lsum[ww][t];
        linv[t] = 1.0f / v;
    }
    __syncthreads();

    // emit tiles (H only): position kk holds vt[n0 + sigma(kk)][c]
    if (t < 256) {
        const int c = t >> 2, kkg = t & 3;
        bf16x8 H;
        #pragma unroll
        for (int jj = 0; jj < 8; ++jj) {
            int n_rd = (kkg >> 1)*16 + 4*(kkg & 1) + (jj & 3) + 8*((jj >> 2) & 1);
            H[jj] = (short)bf_hi(vbs[n_rd][c] * linv[n_rd]);
        }
        unsigned short* tile = (unsigned short*)(base + OFF_T) + (size_t)(n0 >> 5) * 4096;
        *(bf16x8*)(tile + c*32 + kkg*8) = H;
    }
}

// ---------------------------------------------------------------------------
// Kernel 2: sa[c][m] = sum_n bf16(vt[n][c]) * p~[n][m], p~ = bf16trunc(exp2(S)).
// BEST MEASURED CONFIG (137.3 us total): (512,2), S-stage pipeline (iter 'it'
// consumes S computed in it-1; logits(it+1) issue between pack-kp1 and PV-kp1),
// A-frags 2-ahead, tiles prefetched 1-ahead. Reverted here after R17 (macro
// dbuf, 143.0) and R18 (2-chunk MLP, 148.2) both regressed with VGPR pinned
// at 88 — hipcc will not hold deeper register pipelines for this body.
// ---------------------------------------------------------------------------
__global__ __launch_bounds__(512, 2) void attn_kernel(
    const float* __restrict__ x1, const float* __restrict__ x2,
    const float* __restrict__ ga1, const float* __restrict__ ga2,
    const float* __restrict__ ws, float* __restrict__ out_)
{
    int a, bidx;
    xcd_map(blockIdx.x + (int)gridDim.x * blockIdx.y, a, bidx);   // lin 0..255
    const float* x = a ? x2 : x1;
    const float gamma = a ? ga2[0] : ga1[0];
    const float* base = ws + (size_t)a * WSP;
    const unsigned short* F16 = (const unsigned short*)base;
    const unsigned short* G16 = (const unsigned short*)(base + OFF_G);
    const unsigned short* tiles = (const unsigned short*)(base + OFF_T);
    float* out = out_ + (size_t)a * ((size_t)64 * N);

    const int m0 = bidx * 64;
    const int t = threadIdx.x;
    const int w = t >> 6, lane = t & 63, l31 = lane & 31, hi = lane >> 5;

    // g fragments for the wave's TWO 32-col m-groups (resident all kernel)
    const bf16x8 z8 = {0,0,0,0,0,0,0,0};
    bf16x8 Bh0, Bl0, Bh1, Bl1;
    {
        const unsigned short* gp0 = G16 + (size_t)(m0 + l31)*16;
        const unsigned short* gp1 = G16 + (size_t)(m0 + 32 + l31)*16;
        Bh0 = *(const bf16x8*)gp0;
        Bl0 = hi ? z8 : *(const bf16x8*)(gp0 + 8);
        Bh1 = *(const bf16x8*)gp1;
        Bl1 = hi ? z8 : *(const bf16x8*)(gp1 + 8);
    }

    f32x16 accA = ZERO16, accB = ZERO16;   // mg0: ct=0, ct=1
    f32x16 accC = ZERO16, accD = ZERO16;   // mg1: ct=0, ct=1

    const int kbeg = w * (N/8);            // 8 waves, power-of-2 K-split
    const int KM = (N/8) - 1;              // wrap mask (row units)

    bf16x8 Acur, Anxt;             // A-frags: current-logit + 1-ahead
    bf16x8 AH[4];                  // PV tiles for the CURRENT iteration
    f32x16 S0, S1;                 // logits for the CURRENT iteration

    // prologue: S(0) from A(0); Anxt=A(1)/A(2) in flight; tiles(0)
    Acur = *(const bf16x8*)(F16 + (size_t)(kbeg + l31)*16 + hi*8);
    S0 = __builtin_amdgcn_mfma_f32_32x32x16_bf16(Acur, Bh0, ZERO16, 0, 0, 0);
    S1 = __builtin_amdgcn_mfma_f32_32x32x16_bf16(Acur, Bh1, ZERO16, 0, 0, 0);
    S0 = __builtin_amdgcn_mfma_f32_32x32x16_bf16(Acur, Bl0, S0, 0, 0, 0);
    S1 = __builtin_amdgcn_mfma_f32_32x32x16_bf16(Acur, Bl1, S1, 0, 0, 0);
    Acur = *(const bf16x8*)(F16 + (size_t)(kbeg + 32 + l31)*16 + hi*8);
    Anxt = *(const bf16x8*)(F16 + (size_t)(kbeg + 64 + l31)*16 + hi*8);
    {
        const unsigned short* tb = tiles + (size_t)(kbeg >> 5) * 4096;
        #pragma unroll
        for (int kp = 0; kp < 2; ++kp)
            #pragma unroll
            for (int ct = 0; ct < 2; ++ct)
                AH[kp*2+ct] = *(const bf16x8*)(tb + (ct*32 + l31)*32 + kp*16 + hi*8);
    }

    union BU { bf16x8 v; unsigned u[4]; };

    for (int it = 0; it < 32; ++it) {
        // ---- pack kp0 from S[0..7] (S computed in prev iter: no MFMA wait) ----
        BU pH0a, pH1a;
        #pragma unroll
        for (int d = 0; d < 4; ++d) {
            float q0 = EXP2(S0[2*d]);
            float q1 = EXP2(S0[2*d + 1]);
            pH0a.u[d] = pack_hi16(__float_as_uint(q1), __float_as_uint(q0));
            float q2 = EXP2(S1[2*d]);
            float q3 = EXP2(S1[2*d + 1]);
            pH1a.u[d] = pack_hi16(__float_as_uint(q3), __float_as_uint(q2));
        }
        // ---- PV kp0 ----
        accA = __builtin_amdgcn_mfma_f32_32x32x16_bf16(AH[0], pH0a.v, accA, 0, 0, 0);
        accC = __builtin_amdgcn_mfma_f32_32x32x16_bf16(AH[0], pH1a.v, accC, 0, 0, 0);
        accB = __builtin_amdgcn_mfma_f32_32x32x16_bf16(AH[1], pH0a.v, accB, 0, 0, 0);
        accD = __builtin_amdgcn_mfma_f32_32x32x16_bf16(AH[1], pH1a.v, accD, 0, 0, 0);

        // ---- pack kp1 from S[8..15] ----
        BU pH0b, pH1b;
        #pragma unroll
        for (int d = 0; d < 4; ++d) {
            float q0 = EXP2(S0[8 + 2*d]);
            float q1 = EXP2(S0[8 + 2*d + 1]);
            pH0b.u[d] = pack_hi16(__float_as_uint(q1), __float_as_uint(q0));
            float q2 = EXP2(S1[8 + 2*d]);
            float q3 = EXP2(S1[8 + 2*d + 1]);
            pH1b.u[d] = pack_hi16(__float_as_uint(q3), __float_as_uint(q2));
        }

        // ---- logits(it+1) into S (S regs dead after packs above) ----
        S0 = __builtin_amdgcn_mfma_f32_32x32x16_bf16(Acur, Bh0, ZERO16, 0, 0, 0);
        S1 = __builtin_amdgcn_mfma_f32_32x32x16_bf16(Acur, Bh1, ZERO16, 0, 0, 0);
        S0 = __builtin_amdgcn_mfma_f32_32x32x16_bf16(Acur, Bl0, S0, 0, 0, 0);
        S1 = __builtin_amdgcn_mfma_f32_32x32x16_bf16(Acur, Bl1, S1, 0, 0, 0);
        Acur = Anxt;
        // A for it+3's logits (2-ahead of the logit computation; wraps harmlessly)
        Anxt = *(const bf16x8*)(F16 + (size_t)(kbeg + (((it+3)*32) & KM) + l31)*16 + hi*8);

        // ---- PV kp1 (covers logit MFMA latency) ----
        accA = __builtin_amdgcn_mfma_f32_32x32x16_bf16(AH[2], pH0b.v, accA, 0, 0, 0);
        accC = __builtin_amdgcn_mfma_f32_32x32x16_bf16(AH[2], pH1b.v, accC, 0, 0, 0);
        accB = __builtin_amdgcn_mfma_f32_32x32x16_bf16(AH[3], pH0b.v, accB, 0, 0, 0);
        accD = __builtin_amdgcn_mfma_f32_32x32x16_bf16(AH[3], pH1b.v, accD, 0, 0, 0);

        // ---- prefetch tiles(it+1) (after last use of AH) ----
        {
            const unsigned short* tb = tiles
                + (size_t)((kbeg + (((it+1)*32) & KM)) >> 5) * 4096;
            #pragma unroll
            for (int kp = 0; kp < 2; ++kp)
                #pragma unroll
                for (int ct = 0; ct < 2; ++ct)
                    AH[kp*2+ct] = *(const bf16x8*)(tb + (ct*32 + l31)*32 + kp*16 + hi*8);
        }
    }

    // cross-wave (K-split) reduction over 8 waves; 64c x 64m block tile
    __shared__ float red[64][65];
    for (int ww = 0; ww < 8; ++ww) {
        if (w == ww) {
            #pragma unroll
            for (int mg = 0; mg < 2; ++mg)
                #pragma unroll
                for (int ct = 0; ct < 2; ++ct) {
                    const f32x16& Ac = mg ? (ct ? accD : accC) : (ct ? accB : accA);
                    #pragma unroll
                    for (int r = 0; r < 16; ++r) {
                        int c = ct*32 + (r & 3) + 8*(r >> 2) + 4*hi;   // C/D row map
                        int m = mg*32 + l31;
                        if (ww == 0) red[c][m]  = Ac[r];
                        else         red[c][m] += Ac[r];
                    }
                }
        }
        __syncthreads();
    }
    #pragma unroll
    for (int i = 0; i < 8; ++i) {
        int e = t + 512*i;
        int c = e >> 6, m = e & 63;
        size_t gi = (size_t)c*N + m0 + m;
        float xv = __builtin_nontemporal_load(x + gi);
        __builtin_nontemporal_store(gamma * red[c][m] + xv, out + gi);
    }
}

// ---------------------------------------------------------------------------
extern "C" void kernel_launch(void* const* d_in, const int* in_sizes, int n_in,
                              void* d_out, int out_size, void* d_ws, size_t ws_size,
                              hipStream_t stream)
{
    (void)in_sizes; (void)n_in; (void)out_size; (void)ws_size;
    const float* x1  = (const float*)d_in[0];
    const float* x2  = (const float*)d_in[1];
    const float* Wf  = (const float*)d_in[2];
    const float* bf  = (const float*)d_in[3];
    const float* Wg  = (const float*)d_in[4];
    const float* bg  = (const float*)d_in[5];
    const float* Wh1 = (const float*)d_in[6];
    const float* bh1 = (const float*)d_in[7];
    const float* Wh2 = (const float*)d_in[8];
    const float* bh2 = (const float*)d_in[9];
    const float* g1  = (const float*)d_in[10];
    const float* g2  = (const float*)d_in[11];
    float* out = (float*)d_out;
    float* ws  = (float*)d_ws;

    prep_kernel   <<<dim3(N/32, 2), dim3(512), 0, stream>>>(x1,x2,Wf,bf,Wg,bg,Wh1,bh1,Wh2,bh2,ws);
    rownorm_kernel<<<dim3(N/32, 2), dim3(512), 0, stream>>>(ws);
    attn_kernel   <<<dim3(N/64, 2), dim3(512), 0, stream>>>(x1,x2,g1,g2,ws,out);
}